// Round 4
// baseline (190.728 us; speedup 1.0000x reference)
//
#include <hip/hip_runtime.h>

#define BATCH 4
#define SEQ   4096
#define CDIM  1024
#define DDIM  64
#define NROW  (BATCH * SEQ)   // 16384
#define SP    72              // proj W-tile LDS stride (f16)
#define SPB   72              // attn P-tile LDS stride (f16), rows 16B-aligned

typedef _Float16 f16;
typedef _Float16 f16x8 __attribute__((ext_vector_type(8)));
typedef _Float16 f16x4 __attribute__((ext_vector_type(4)));
typedef __fp16   h16x2 __attribute__((ext_vector_type(2)));  // cvt_pkrtz return type
typedef float    f32x4 __attribute__((ext_vector_type(4)));

#define MFMA16(a, b, c) __builtin_amdgcn_mfma_f32_16x16x32_f16((a), (b), (c), 0, 0, 0)

// scores = (q·k)*8 (the /scale bug); softmax in exp2 domain => fold 8*log2(e) into q
#define QSCALE 11.5415603f

__device__ inline f16x8 cvt8(f32x4 a, f32x4 b) {
  h16x2 p0 = __builtin_amdgcn_cvt_pkrtz(a[0], a[1]);
  h16x2 p1 = __builtin_amdgcn_cvt_pkrtz(a[2], a[3]);
  h16x2 p2 = __builtin_amdgcn_cvt_pkrtz(b[0], b[1]);
  h16x2 p3 = __builtin_amdgcn_cvt_pkrtz(b[2], b[3]);
  f16x8 r;
  r[0] = p0[0]; r[1] = p0[1]; r[2] = p1[0]; r[3] = p1[1];
  r[4] = p2[0]; r[5] = p2[1]; r[6] = p3[0]; r[7] = p3[1];
  return r;
}

__device__ inline f16x4 cvt4(float a, float b, float c, float d) {
  h16x2 lo = __builtin_amdgcn_cvt_pkrtz(a, b);
  h16x2 hi = __builtin_amdgcn_cvt_pkrtz(c, d);
  f16x4 r;
  r[0] = lo[0]; r[1] = lo[1]; r[2] = hi[0]; r[3] = hi[1];
  return r;
}

// ---------------- fused QKV projection (W converted inline, no prep kernel) ----
__global__ __launch_bounds__(256) void proj_kernel(const float* __restrict__ x,
                                                   const float* __restrict__ Wq,
                                                   const float* __restrict__ Wk,
                                                   const float* __restrict__ Wv,
                                                   const float* __restrict__ bq,
                                                   const float* __restrict__ bk,
                                                   const float* __restrict__ bv,
                                                   f16* __restrict__ qs,
                                                   f16* __restrict__ ks,
                                                   f16* __restrict__ vT) {
  __shared__ __attribute__((aligned(16))) f16 lw[192][SP];
  const int tid = threadIdx.x;
  const int lane = tid & 63, w = tid >> 6;
  const int n = lane & 15, quad = lane >> 4;
  const int rowbase = blockIdx.x * 64 + w * 16;
  const int srow = tid >> 2;        // 0..63
  const int scol = (tid & 3) * 8;   // 0,8,16,24

  const float* Wm[3] = {Wq, Wk, Wv};

  f32x4 acc[3][4];
#pragma unroll
  for (int m_ = 0; m_ < 3; ++m_)
#pragma unroll
    for (int t_ = 0; t_ < 4; ++t_) acc[m_][t_] = (f32x4){0.f, 0.f, 0.f, 0.f};

  const float* xrow = x + (size_t)(rowbase + n) * CDIM + quad * 8;

  f32x4 wr[3][2];
  f32x4 xr0, xr1;
#define WLOAD(KC)                                                          \
  {                                                                        \
    _Pragma("unroll") for (int i = 0; i < 3; ++i) {                        \
      const float* p = Wm[i] + (size_t)srow * CDIM + (KC) + scol;          \
      wr[i][0] = *(const f32x4*)p;                                         \
      wr[i][1] = *(const f32x4*)(p + 4);                                   \
    }                                                                      \
  }
#define XLOAD(KC)                          \
  {                                        \
    xr0 = *(const f32x4*)(xrow + (KC));    \
    xr1 = *(const f32x4*)(xrow + (KC) + 4); \
  }

  WLOAD(0);
  XLOAD(0);
  for (int kc = 0; kc < CDIM; kc += 32) {
#pragma unroll
    for (int i = 0; i < 3; ++i) *(f16x8*)&lw[i * 64 + srow][scol] = cvt8(wr[i][0], wr[i][1]);
    __syncthreads();
    if (kc + 32 < CDIM) WLOAD(kc + 32);
    const f16x8 a = cvt8(xr0, xr1);
    if (kc + 32 < CDIM) XLOAD(kc + 32);
#pragma unroll
    for (int mat = 0; mat < 3; ++mat)
#pragma unroll
      for (int tile = 0; tile < 4; ++tile) {
        const f16x8 bf = *(const f16x8*)&lw[mat * 64 + tile * 16 + n][quad * 8];
        acc[mat][tile] = MFMA16(a, bf, acc[mat][tile]);
      }
    __syncthreads();
  }

  const float* bias_p[3] = {bq, bk, bv};
#pragma unroll
  for (int mat = 0; mat < 3; ++mat)
#pragma unroll
    for (int tile = 0; tile < 4; ++tile) {
      const int d = tile * 16 + n;
      const float bias = bias_p[mat][d];
      const int row0 = rowbase + quad * 4;   // C-layout: row=quad*4+r, col=n
      f32x4 a = acc[mat][tile];
      if (mat == 0) {
#pragma unroll
        for (int r = 0; r < 4; ++r)
          qs[(size_t)(row0 + r) * DDIM + d] = (f16)((a[r] + bias) * QSCALE);
      } else if (mat == 1) {
#pragma unroll
        for (int r = 0; r < 4; ++r)
          ks[(size_t)(row0 + r) * DDIM + d] = (f16)(a[r] + bias);
      } else {
        const int bb = row0 >> 12;
        const int t = row0 & (SEQ - 1);
        f16x4 pk = cvt4(a[0] + bias, a[1] + bias, a[2] + bias, a[3] + bias);
        *(f16x4*)(vT + (size_t)(bb * 64 + d) * SEQ + t) = pk;
      }
    }
}

// ---------------- flash attention, transposed dataflow ----------------
// S' = K·Q^T  (C-layout: row=key, col=q) -> per-lane softmax state per q-column.
// O^T = V^T·P^T (A=V^T rows of vT, B=P^T from tiny LDS transpose).
// No __syncthreads; K/V fragments read directly from global (L1/L2).
// Wave: 32 q-rows (2 groups of 16), 64-key chunks, K frags double-buffered.
template <int NSPLIT>
__global__ __launch_bounds__(256, 2) void attn_kernel(const f16* __restrict__ qs,
                                                      const f16* __restrict__ ks,
                                                      const f16* __restrict__ vT,
                                                      float* __restrict__ outp,
                                                      float* __restrict__ pm,
                                                      float* __restrict__ pl) {
  __shared__ __attribute__((aligned(16))) f16 pb[4][32][SPB];
  const int tid = threadIdx.x, lane = tid & 63, w = tid >> 6;
  const int n = lane & 15, quad = lane >> 4;
  const int split = blockIdx.x & (NSPLIT - 1);
  const int rowgrp = (blockIdx.x / NSPLIT) * 4 + w;  // 0..511
  const int row0 = rowgrp * 32;
  const int bb = row0 >> 12;
  const int kbase = split * (SEQ / NSPLIT);
  const int NC = SEQ / NSPLIT / 64;  // 16 / 32 / 64 — always even

  const f16* kb = ks + (size_t)bb * SEQ * DDIM;
  const f16* vb = vT + (size_t)bb * DDIM * SEQ;

  // Q fragments (B-operand): B[k=d=quad*8+j][col=q=n], persistent
  f16x8 qf[2][2];
#pragma unroll
  for (int g = 0; g < 2; ++g)
#pragma unroll
    for (int h = 0; h < 2; ++h)
      qf[g][h] = *(const f16x8*)(qs + (size_t)(row0 + g * 16 + n) * DDIM + h * 32 + quad * 8);

  f32x4 acc[2][4];
  float m[2] = {-1e30f, -1e30f}, ll[2] = {0.f, 0.f};
#pragma unroll
  for (int g = 0; g < 2; ++g)
#pragma unroll
    for (int t = 0; t < 4; ++t) acc[g][t] = (f32x4){0.f, 0.f, 0.f, 0.f};

  f16x8 kfA[4][2], kfB[4][2], vf[4][2];

  auto kload = [&](f16x8(&DST)[4][2], int kb0) {
#pragma unroll
    for (int st = 0; st < 4; ++st)
#pragma unroll
      for (int h = 0; h < 2; ++h)
        DST[st][h] = *(const f16x8*)(kb + (size_t)(kb0 + st * 16 + n) * DDIM + h * 32 + quad * 8);
  };
  auto vload = [&](int kb0) {
#pragma unroll
    for (int t = 0; t < 4; ++t)
#pragma unroll
      for (int kk = 0; kk < 2; ++kk)
        vf[t][kk] = *(const f16x8*)(vb + (size_t)(t * 16 + n) * SEQ + kb0 + kk * 32 + quad * 8);
  };

  auto chunk = [&](f16x8(&KF)[4][2], f16x8(&KN)[4][2], int c) {
    const int kb0 = kbase + c * 64;
    vload(kb0);
    // S' tiles: D[m=key st*16+quad*4+r][n=q]
    f32x4 s[2][4];
#pragma unroll
    for (int g = 0; g < 2; ++g)
#pragma unroll
      for (int st = 0; st < 4; ++st) {
        f32x4 z = (f32x4){0.f, 0.f, 0.f, 0.f};
        z = MFMA16(KF[st][0], qf[g][0], z);
        s[g][st] = MFMA16(KF[st][1], qf[g][1], z);
      }
    const int cn = (c + 1 < NC) ? (c + 1) : (NC - 1);
    kload(KN, kbase + cn * 64);  // prefetch next chunk's K (clamped, dead on last)

    __builtin_amdgcn_wave_barrier();  // order vs previous chunk's pb reads
#pragma unroll
    for (int g = 0; g < 2; ++g) {
      f32x4 mx;
#pragma unroll
      for (int r = 0; r < 4; ++r)
        mx[r] = fmaxf(fmaxf(s[g][0][r], s[g][1][r]), fmaxf(s[g][2][r], s[g][3][r]));
      float mloc = fmaxf(fmaxf(mx[0], mx[1]), fmaxf(mx[2], mx[3]));
      mloc = fmaxf(mloc, __shfl_xor(mloc, 16));
      mloc = fmaxf(mloc, __shfl_xor(mloc, 32));
      const float mnew = fmaxf(m[g], mloc);
      const float alpha = __builtin_amdgcn_exp2f(m[g] - mnew);
      m[g] = mnew;
      float psum = 0.f;
#pragma unroll
      for (int st = 0; st < 4; ++st) {
        f32x4 p;
#pragma unroll
        for (int r = 0; r < 4; ++r) p[r] = __builtin_amdgcn_exp2f(s[g][st][r] - mnew);
        psum += (p[0] + p[1]) + (p[2] + p[3]);
        // lane holds 4 CONSECUTIVE keys of q-row n: one b64 write
        *(f16x4*)&pb[w][g * 16 + n][st * 16 + quad * 4] = cvt4(p[0], p[1], p[2], p[3]);
      }
      ll[g] = ll[g] * alpha + psum;
#pragma unroll
      for (int t = 0; t < 4; ++t) acc[g][t] *= alpha;
    }
    __builtin_amdgcn_wave_barrier();
#pragma unroll
    for (int g = 0; g < 2; ++g) {
      const f16x8 pa0 = *(const f16x8*)&pb[w][g * 16 + n][quad * 8];
      const f16x8 pa1 = *(const f16x8*)&pb[w][g * 16 + n][32 + quad * 8];
#pragma unroll
      for (int t = 0; t < 4; ++t) {
        acc[g][t] = MFMA16(vf[t][0], pa0, acc[g][t]);
        acc[g][t] = MFMA16(vf[t][1], pa1, acc[g][t]);
      }
    }
  };

  kload(kfA, kbase);
  for (int c = 0; c < NC; c += 2) {
    chunk(kfA, kfB, c);
    chunk(kfB, kfA, c + 1);
  }

  // final cross-quad l reduction (m already synchronized across quads)
  float lred[2];
#pragma unroll
  for (int g = 0; g < 2; ++g) {
    float l = ll[g];
    l += __shfl_xor(l, 16);
    l += __shfl_xor(l, 32);
    lred[g] = l;
  }

  if (NSPLIT == 1) {
#pragma unroll
    for (int g = 0; g < 2; ++g) {
      const float inv = 1.0f / lred[g];
      const int q = row0 + g * 16 + n;
#pragma unroll
      for (int t = 0; t < 4; ++t) {
        f32x4 o = acc[g][t];
#pragma unroll
        for (int r = 0; r < 4; ++r) o[r] *= inv;
        *(f32x4*)(outp + (size_t)q * DDIM + t * 16 + quad * 4) = o;
      }
    }
  } else {
#pragma unroll
    for (int g = 0; g < 2; ++g) {
      const int q = row0 + g * 16 + n;
#pragma unroll
      for (int t = 0; t < 4; ++t)
        *(f32x4*)(outp + ((size_t)split * NROW + q) * DDIM + t * 16 + quad * 4) = acc[g][t];
      if (quad == 0) {
        pm[split * NROW + q] = m[g];
        pl[split * NROW + q] = lred[g];
      }
    }
  }
}

// ---------------- split-K combine ----------------
template <int NSPLIT>
__global__ __launch_bounds__(256) void combine_kernel(const float* __restrict__ pacc,
                                                      const float* __restrict__ pm,
                                                      const float* __restrict__ pl,
                                                      float* __restrict__ out) {
  const int idx = blockIdx.x * 256 + threadIdx.x;  // NROW*16 units
  const int row = idx >> 4;
  const int c = (idx & 15) * 4;
  float mm = pm[row];
#pragma unroll
  for (int s = 1; s < NSPLIT; ++s) mm = fmaxf(mm, pm[s * NROW + row]);
  float L = 0.f;
  f32x4 o = (f32x4){0.f, 0.f, 0.f, 0.f};
#pragma unroll
  for (int s = 0; s < NSPLIT; ++s) {
    const float e = __builtin_amdgcn_exp2f(pm[s * NROW + row] - mm);
    L += pl[s * NROW + row] * e;
    const f32x4 a = *(const f32x4*)(pacc + ((size_t)s * NROW + row) * DDIM + c);
#pragma unroll
    for (int j = 0; j < 4; ++j) o[j] += a[j] * e;
  }
  const float inv = 1.0f / L;
#pragma unroll
  for (int j = 0; j < 4; ++j) o[j] *= inv;
  *(f32x4*)(out + (size_t)row * DDIM + c) = o;
}

extern "C" void kernel_launch(void* const* d_in, const int* in_sizes, int n_in,
                              void* d_out, int out_size, void* d_ws, size_t ws_size,
                              hipStream_t stream) {
  const float* x  = (const float*)d_in[0];
  const float* Wq = (const float*)d_in[1];
  const float* bq = (const float*)d_in[2];
  const float* Wk = (const float*)d_in[3];
  const float* bk = (const float*)d_in[4];
  const float* Wv = (const float*)d_in[5];
  const float* bv = (const float*)d_in[6];
  float* out = (float*)d_out;

  f16* qs = (f16*)d_ws;
  f16* ks = qs + (size_t)NROW * DDIM;
  f16* vT = ks + (size_t)NROW * DDIM;
  char* endf16 = (char*)(vT + (size_t)NROW * DDIM);

  float* pacc = (float*)endf16;
  const size_t base = (size_t)(endf16 - (char*)d_ws);
  const size_t need4 = base + (size_t)4 * NROW * (DDIM + 2) * 4;
  const size_t need2 = base + (size_t)2 * NROW * (DDIM + 2) * 4;

  proj_kernel<<<dim3(256), dim3(256), 0, stream>>>(x, Wq, Wk, Wv, bq, bk, bv, qs, ks, vT);

  if (ws_size >= need4) {
    float* pm = pacc + (size_t)4 * NROW * DDIM;
    float* pl = pm + (size_t)4 * NROW;
    attn_kernel<4><<<dim3(128 * 4), dim3(256), 0, stream>>>(qs, ks, vT, pacc, pm, pl);
    combine_kernel<4><<<dim3(NROW * 16 / 256), dim3(256), 0, stream>>>(pacc, pm, pl, out);
  } else if (ws_size >= need2) {
    float* pm = pacc + (size_t)2 * NROW * DDIM;
    float* pl = pm + (size_t)2 * NROW;
    attn_kernel<2><<<dim3(128 * 2), dim3(256), 0, stream>>>(qs, ks, vT, pacc, pm, pl);
    combine_kernel<2><<<dim3(NROW * 16 / 256), dim3(256), 0, stream>>>(pacc, pm, pl, out);
  } else {
    attn_kernel<1><<<dim3(128), dim3(256), 0, stream>>>(qs, ks, vT, out, nullptr, nullptr);
  }
}

// Round 5
// 168.808 us; speedup vs baseline: 1.1298x; 1.1298x over previous
//
#include <hip/hip_runtime.h>

#define BATCH 4
#define SEQ   4096
#define CDIM  1024
#define DDIM  64
#define NROW  (BATCH * SEQ)   // 16384
#define SP    72              // proj W-tile LDS stride (f16)
#define SPA   70              // attn LDS stride (f16): 35 dwords, odd-ish -> ~2-way banks

typedef _Float16 f16;
typedef _Float16 f16x8 __attribute__((ext_vector_type(8)));
typedef _Float16 f16x4 __attribute__((ext_vector_type(4)));
typedef __fp16   h16x2 __attribute__((ext_vector_type(2)));  // cvt_pkrtz return type
typedef float    f32x4 __attribute__((ext_vector_type(4)));

#define MFMA16(a, b, c) __builtin_amdgcn_mfma_f32_16x16x32_f16((a), (b), (c), 0, 0, 0)

// scores = (q·k)*8 (the /scale bug); softmax in exp2 domain => fold 8*log2(e) into q
#define QSCALE 11.5415603f

__device__ inline f16x8 cvt8(f32x4 a, f32x4 b) {
  h16x2 p0 = __builtin_amdgcn_cvt_pkrtz(a[0], a[1]);
  h16x2 p1 = __builtin_amdgcn_cvt_pkrtz(a[2], a[3]);
  h16x2 p2 = __builtin_amdgcn_cvt_pkrtz(b[0], b[1]);
  h16x2 p3 = __builtin_amdgcn_cvt_pkrtz(b[2], b[3]);
  f16x8 r;
  r[0] = p0[0]; r[1] = p0[1]; r[2] = p1[0]; r[3] = p1[1];
  r[4] = p2[0]; r[5] = p2[1]; r[6] = p3[0]; r[7] = p3[1];
  return r;
}

__device__ inline f16x4 cvt4(float a, float b, float c, float d) {
  h16x2 lo = __builtin_amdgcn_cvt_pkrtz(a, b);
  h16x2 hi = __builtin_amdgcn_cvt_pkrtz(c, d);
  f16x4 r;
  r[0] = lo[0]; r[1] = lo[1]; r[2] = hi[0]; r[3] = hi[1];
  return r;
}

// ---------------- fused QKV projection ----------------
__global__ __launch_bounds__(256) void proj_kernel(const float* __restrict__ x,
                                                   const float* __restrict__ Wq,
                                                   const float* __restrict__ Wk,
                                                   const float* __restrict__ Wv,
                                                   const float* __restrict__ bq,
                                                   const float* __restrict__ bk,
                                                   const float* __restrict__ bv,
                                                   f16* __restrict__ qs,
                                                   f16* __restrict__ ks,
                                                   f16* __restrict__ vT) {
  __shared__ __attribute__((aligned(16))) f16 lw[192][SP];
  const int tid = threadIdx.x;
  const int lane = tid & 63, w = tid >> 6;
  const int n = lane & 15, quad = lane >> 4;
  const int rowbase = blockIdx.x * 64 + w * 16;
  const int srow = tid >> 2;        // 0..63
  const int scol = (tid & 3) * 8;   // 0,8,16,24

  const float* Wm[3] = {Wq, Wk, Wv};

  f32x4 acc[3][4];
#pragma unroll
  for (int m_ = 0; m_ < 3; ++m_)
#pragma unroll
    for (int t_ = 0; t_ < 4; ++t_) acc[m_][t_] = (f32x4){0.f, 0.f, 0.f, 0.f};

  const float* xrow = x + (size_t)(rowbase + n) * CDIM + quad * 8;

  f32x4 wr[3][2];
  f32x4 xr0, xr1;
#define WLOAD(KC)                                                          \
  {                                                                        \
    _Pragma("unroll") for (int i = 0; i < 3; ++i) {                        \
      const float* p = Wm[i] + (size_t)srow * CDIM + (KC) + scol;          \
      wr[i][0] = *(const f32x4*)p;                                         \
      wr[i][1] = *(const f32x4*)(p + 4);                                   \
    }                                                                      \
  }
#define XLOAD(KC)                          \
  {                                        \
    xr0 = *(const f32x4*)(xrow + (KC));    \
    xr1 = *(const f32x4*)(xrow + (KC) + 4); \
  }

  WLOAD(0);
  XLOAD(0);
  for (int kc = 0; kc < CDIM; kc += 32) {
#pragma unroll
    for (int i = 0; i < 3; ++i) *(f16x8*)&lw[i * 64 + srow][scol] = cvt8(wr[i][0], wr[i][1]);
    __syncthreads();
    if (kc + 32 < CDIM) WLOAD(kc + 32);
    const f16x8 a = cvt8(xr0, xr1);
    if (kc + 32 < CDIM) XLOAD(kc + 32);
#pragma unroll
    for (int mat = 0; mat < 3; ++mat)
#pragma unroll
      for (int tile = 0; tile < 4; ++tile) {
        const f16x8 bf = *(const f16x8*)&lw[mat * 64 + tile * 16 + n][quad * 8];
        acc[mat][tile] = MFMA16(a, bf, acc[mat][tile]);
      }
    __syncthreads();
  }

  const float* bias_p[3] = {bq, bk, bv};
#pragma unroll
  for (int mat = 0; mat < 3; ++mat)
#pragma unroll
    for (int tile = 0; tile < 4; ++tile) {
      const int d = tile * 16 + n;
      const float bias = bias_p[mat][d];
      const int row0 = rowbase + quad * 4;   // C-layout: row=quad*4+r, col=n
      f32x4 a = acc[mat][tile];
      if (mat == 0) {
#pragma unroll
        for (int r = 0; r < 4; ++r)
          qs[(size_t)(row0 + r) * DDIM + d] = (f16)((a[r] + bias) * QSCALE);
      } else if (mat == 1) {
#pragma unroll
        for (int r = 0; r < 4; ++r)
          ks[(size_t)(row0 + r) * DDIM + d] = (f16)(a[r] + bias);
      } else {
        const int bb = row0 >> 12;
        const int t = row0 & (SEQ - 1);
        f16x4 pk = cvt4(a[0] + bias, a[1] + bias, a[2] + bias, a[3] + bias);
        *(f16x4*)(vT + (size_t)(bb * 64 + d) * SEQ + t) = pk;
      }
    }
}

// ---------------- flash attention: transposed softmax + LDS-staged K/V ----------
// S' = K·Q^T (C-layout row=key, col=q) -> per-lane softmax state.
// O^T = V^T·P^T. Block: 4 waves x 32 q-rows = 128 rows; 64-key chunks staged in
// LDS (shared by all 4 waves), register-prefetch of next chunk during compute.
template <int NSPLIT>
__global__ __launch_bounds__(256, 4) void attn_kernel(const f16* __restrict__ qs,
                                                      const f16* __restrict__ ks,
                                                      const f16* __restrict__ vT,
                                                      float* __restrict__ outp,
                                                      float* __restrict__ pm,
                                                      float* __restrict__ pl) {
  __shared__ __attribute__((aligned(16))) f16 lk[64][SPA];     // [key][d]
  __shared__ __attribute__((aligned(16))) f16 lv[64][SPA];     // [d][key]
  __shared__ __attribute__((aligned(16))) f16 pb[4][32][SPA];  // per-wave P^T scratch
  const int tid = threadIdx.x, lane = tid & 63, w = tid >> 6;
  const int n = lane & 15, quad = lane >> 4;
  const int split = blockIdx.x % NSPLIT;
  const int rowblk = blockIdx.x / NSPLIT;       // 0..127
  const int row0 = rowblk * 128 + w * 32;       // wave's 32 q-rows
  const int bb = row0 >> 12;
  const int kbase = split * (SEQ / NSPLIT);
  const int NC = SEQ / NSPLIT / 64;

  const f16* kb = ks + (size_t)bb * SEQ * DDIM;
  const f16* vb = vT + (size_t)bb * DDIM * SEQ;

  // staging: 256 thr x 32 B covers one 64x64 f16 tile per array
  const int srow = tid >> 2;          // 0..63
  const int scol = (tid & 3) * 16;    // 0,16,32,48
  const f16* kgp = kb + (size_t)(kbase + srow) * DDIM + scol;
  const f16* vgp = vb + (size_t)srow * SEQ + kbase + scol;

  // persistent Q B-fragments: B[k=d=quad*8+j][col=q]
  f16x8 qf[2][2];
#pragma unroll
  for (int g = 0; g < 2; ++g)
#pragma unroll
    for (int h = 0; h < 2; ++h)
      qf[g][h] = *(const f16x8*)(qs + (size_t)(row0 + g * 16 + n) * DDIM + h * 32 + quad * 8);

  f32x4 acc[2][4];
  float m[2] = {-1e30f, -1e30f}, ll[2] = {0.f, 0.f};
#pragma unroll
  for (int g = 0; g < 2; ++g)
#pragma unroll
    for (int t = 0; t < 4; ++t) acc[g][t] = (f32x4){0.f, 0.f, 0.f, 0.f};

  f16x8 kr0, kr1, vr0, vr1;
  auto gload = [&](int c) {
    const f16* kp = kgp + (size_t)c * 64 * DDIM;
    kr0 = *(const f16x8*)kp;
    kr1 = *(const f16x8*)(kp + 8);
    const f16* vp = vgp + c * 64;
    vr0 = *(const f16x8*)vp;
    vr1 = *(const f16x8*)(vp + 8);
  };

  gload(0);
  for (int c = 0; c < NC; ++c) {
    *(f16x8*)&lk[srow][scol] = kr0;
    *(f16x8*)&lk[srow][scol + 8] = kr1;
    *(f16x8*)&lv[srow][scol] = vr0;
    *(f16x8*)&lv[srow][scol + 8] = vr1;
    __syncthreads();
    if (c + 1 < NC) gload(c + 1);  // prefetch; drained by end-of-chunk barrier

    // S' = K·Q^T : K A-frags shared across both q-groups
    f32x4 s[2][4];
#pragma unroll
    for (int st = 0; st < 4; ++st) {
      const f16x8 klo = *(const f16x8*)&lk[st * 16 + n][quad * 8];
      const f16x8 khi = *(const f16x8*)&lk[st * 16 + n][32 + quad * 8];
#pragma unroll
      for (int g = 0; g < 2; ++g) {
        f32x4 z = (f32x4){0.f, 0.f, 0.f, 0.f};
        z = MFMA16(klo, qf[g][0], z);
        s[g][st] = MFMA16(khi, qf[g][1], z);
      }
    }

    // per-lane online softmax (column q = n owned by lanes n, n+16, n+32, n+48)
#pragma unroll
    for (int g = 0; g < 2; ++g) {
      f32x4 mx;
#pragma unroll
      for (int r = 0; r < 4; ++r)
        mx[r] = fmaxf(fmaxf(s[g][0][r], s[g][1][r]), fmaxf(s[g][2][r], s[g][3][r]));
      float mloc = fmaxf(fmaxf(mx[0], mx[1]), fmaxf(mx[2], mx[3]));
      mloc = fmaxf(mloc, __shfl_xor(mloc, 16));
      mloc = fmaxf(mloc, __shfl_xor(mloc, 32));
      const float mnew = fmaxf(m[g], mloc);
      const float alpha = __builtin_amdgcn_exp2f(m[g] - mnew);
      m[g] = mnew;
      float psum = 0.f;
#pragma unroll
      for (int st = 0; st < 4; ++st) {
        f32x4 p;
#pragma unroll
        for (int r = 0; r < 4; ++r) p[r] = __builtin_amdgcn_exp2f(s[g][st][r] - mnew);
        psum += (p[0] + p[1]) + (p[2] + p[3]);
        // lane holds 4 consecutive keys of q-row n: one b64 write
        *(f16x4*)&pb[w][g * 16 + n][st * 16 + quad * 4] = cvt4(p[0], p[1], p[2], p[3]);
      }
      ll[g] = ll[g] * alpha + psum;
#pragma unroll
      for (int t = 0; t < 4; ++t) acc[g][t] *= alpha;
    }
    __builtin_amdgcn_wave_barrier();  // pb is per-wave: wave-local ordering only

    // O^T += V^T·P^T : V A-frags shared across both q-groups
#pragma unroll
    for (int g = 0; g < 2; ++g) {
      const f16x8 pa0 = *(const f16x8*)&pb[w][g * 16 + n][quad * 8];
      const f16x8 pa1 = *(const f16x8*)&pb[w][g * 16 + n][32 + quad * 8];
#pragma unroll
      for (int t = 0; t < 4; ++t) {
        const f16x8 vlo = *(const f16x8*)&lv[t * 16 + n][quad * 8];
        const f16x8 vhi = *(const f16x8*)&lv[t * 16 + n][32 + quad * 8];
        acc[g][t] = MFMA16(vlo, pa0, acc[g][t]);
        acc[g][t] = MFMA16(vhi, pa1, acc[g][t]);
      }
    }
    __syncthreads();
  }

  float lred[2];
#pragma unroll
  for (int g = 0; g < 2; ++g) {
    float l = ll[g];
    l += __shfl_xor(l, 16);
    l += __shfl_xor(l, 32);
    lred[g] = l;
  }

  if (NSPLIT == 1) {
#pragma unroll
    for (int g = 0; g < 2; ++g) {
      const float inv = 1.0f / lred[g];
      const int q = row0 + g * 16 + n;
#pragma unroll
      for (int t = 0; t < 4; ++t) {
        f32x4 o = acc[g][t];
#pragma unroll
        for (int r = 0; r < 4; ++r) o[r] *= inv;
        *(f32x4*)(outp + (size_t)q * DDIM + t * 16 + quad * 4) = o;
      }
    }
  } else {
#pragma unroll
    for (int g = 0; g < 2; ++g) {
      const int q = row0 + g * 16 + n;
#pragma unroll
      for (int t = 0; t < 4; ++t)
        *(f32x4*)(outp + ((size_t)split * NROW + q) * DDIM + t * 16 + quad * 4) = acc[g][t];
      if (quad == 0) {
        pm[split * NROW + q] = m[g];
        pl[split * NROW + q] = lred[g];
      }
    }
  }
}

// ---------------- split-K combine ----------------
template <int NSPLIT>
__global__ __launch_bounds__(256) void combine_kernel(const float* __restrict__ pacc,
                                                      const float* __restrict__ pm,
                                                      const float* __restrict__ pl,
                                                      float* __restrict__ out) {
  const int idx = blockIdx.x * 256 + threadIdx.x;  // NROW*16 units
  const int row = idx >> 4;
  const int c = (idx & 15) * 4;
  float mm = pm[row];
#pragma unroll
  for (int s = 1; s < NSPLIT; ++s) mm = fmaxf(mm, pm[s * NROW + row]);
  float L = 0.f;
  f32x4 o = (f32x4){0.f, 0.f, 0.f, 0.f};
#pragma unroll
  for (int s = 0; s < NSPLIT; ++s) {
    const float e = __builtin_amdgcn_exp2f(pm[s * NROW + row] - mm);
    L += pl[s * NROW + row] * e;
    const f32x4 a = *(const f32x4*)(pacc + ((size_t)s * NROW + row) * DDIM + c);
#pragma unroll
    for (int j = 0; j < 4; ++j) o[j] += a[j] * e;
  }
  const float inv = 1.0f / L;
#pragma unroll
  for (int j = 0; j < 4; ++j) o[j] *= inv;
  *(f32x4*)(out + (size_t)row * DDIM + c) = o;
}

extern "C" void kernel_launch(void* const* d_in, const int* in_sizes, int n_in,
                              void* d_out, int out_size, void* d_ws, size_t ws_size,
                              hipStream_t stream) {
  const float* x  = (const float*)d_in[0];
  const float* Wq = (const float*)d_in[1];
  const float* bq = (const float*)d_in[2];
  const float* Wk = (const float*)d_in[3];
  const float* bk = (const float*)d_in[4];
  const float* Wv = (const float*)d_in[5];
  const float* bv = (const float*)d_in[6];
  float* out = (float*)d_out;

  f16* qs = (f16*)d_ws;
  f16* ks = qs + (size_t)NROW * DDIM;
  f16* vT = ks + (size_t)NROW * DDIM;
  char* endf16 = (char*)(vT + (size_t)NROW * DDIM);

  float* pacc = (float*)endf16;
  const size_t base = (size_t)(endf16 - (char*)d_ws);
  const size_t need8 = base + (size_t)8 * NROW * (DDIM + 2) * 4;
  const size_t need4 = base + (size_t)4 * NROW * (DDIM + 2) * 4;

  proj_kernel<<<dim3(256), dim3(256), 0, stream>>>(x, Wq, Wk, Wv, bq, bk, bv, qs, ks, vT);

  if (ws_size >= need8) {
    float* pm = pacc + (size_t)8 * NROW * DDIM;
    float* pl = pm + (size_t)8 * NROW;
    attn_kernel<8><<<dim3(128 * 8), dim3(256), 0, stream>>>(qs, ks, vT, pacc, pm, pl);
    combine_kernel<8><<<dim3(NROW * 16 / 256), dim3(256), 0, stream>>>(pacc, pm, pl, out);
  } else if (ws_size >= need4) {
    float* pm = pacc + (size_t)4 * NROW * DDIM;
    float* pl = pm + (size_t)4 * NROW;
    attn_kernel<4><<<dim3(128 * 4), dim3(256), 0, stream>>>(qs, ks, vT, pacc, pm, pl);
    combine_kernel<4><<<dim3(NROW * 16 / 256), dim3(256), 0, stream>>>(pacc, pm, pl, out);
  } else {
    attn_kernel<1><<<dim3(128), dim3(256), 0, stream>>>(qs, ks, vT, out, nullptr, nullptr);
  }
}

// Round 6
// 164.536 us; speedup vs baseline: 1.1592x; 1.0260x over previous
//
#include <hip/hip_runtime.h>

#define BATCH 4
#define SEQ   4096
#define CDIM  1024
#define DDIM  64
#define NROW  (BATCH * SEQ)   // 16384
#define SPW   40              // proj W-tile LDS stride (f16) for 32-ch chunks
#define SPA   70              // attn LDS stride (f16)
#define NSPL  8

typedef _Float16 f16;
typedef _Float16 f16x8 __attribute__((ext_vector_type(8)));
typedef _Float16 f16x4 __attribute__((ext_vector_type(4)));
typedef __fp16   h16x2 __attribute__((ext_vector_type(2)));  // cvt_pkrtz return type
typedef float    f32x4 __attribute__((ext_vector_type(4)));

#define MFMA32(a, b, c) __builtin_amdgcn_mfma_f32_16x16x32_f16((a), (b), (c), 0, 0, 0)
#define MFMA16(a, b, c) __builtin_amdgcn_mfma_f32_16x16x16f16((a), (b), (c), 0, 0, 0)

// scores = (q·k)*8 (the /scale bug); softmax in exp2 domain => fold 8*log2(e) into q
#define QSCALE 11.5415603f

__device__ inline f16x8 cvt8(f32x4 a, f32x4 b) {
  h16x2 p0 = __builtin_amdgcn_cvt_pkrtz(a[0], a[1]);
  h16x2 p1 = __builtin_amdgcn_cvt_pkrtz(a[2], a[3]);
  h16x2 p2 = __builtin_amdgcn_cvt_pkrtz(b[0], b[1]);
  h16x2 p3 = __builtin_amdgcn_cvt_pkrtz(b[2], b[3]);
  f16x8 r;
  r[0] = p0[0]; r[1] = p0[1]; r[2] = p1[0]; r[3] = p1[1];
  r[4] = p2[0]; r[5] = p2[1]; r[6] = p3[0]; r[7] = p3[1];
  return r;
}

__device__ inline f16x4 cvt4(float a, float b, float c, float d) {
  h16x2 lo = __builtin_amdgcn_cvt_pkrtz(a, b);
  h16x2 hi = __builtin_amdgcn_cvt_pkrtz(c, d);
  f16x4 r;
  r[0] = lo[0]; r[1] = lo[1]; r[2] = hi[0]; r[3] = hi[1];
  return r;
}

// ---------------- W fp32 -> f16 prep (once; proj re-reads f16 from L2) --------
__global__ __launch_bounds__(256) void prep_w_kernel(const float* __restrict__ Wq,
                                                     const float* __restrict__ Wk,
                                                     const float* __restrict__ Wv,
                                                     f16* __restrict__ wf) {
  const int i = (blockIdx.x * 256 + threadIdx.x) * 4;  // 64 blocks cover 65536
  f32x4 a = *(const f32x4*)(Wq + i);
  f32x4 b = *(const f32x4*)(Wk + i);
  f32x4 c = *(const f32x4*)(Wv + i);
  *(f16x4*)(wf + i)          = cvt4(a[0], a[1], a[2], a[3]);
  *(f16x4*)(wf + 65536 + i)  = cvt4(b[0], b[1], b[2], b[3]);
  *(f16x4*)(wf + 131072 + i) = cvt4(c[0], c[1], c[2], c[3]);
}

// ---------------- fused QKV projection, channel-split across wave pairs -------
// 512 blocks x 256 thr; 32 rows/block. Waves 0,1: rows {0,16}+base, ch [0,512);
// waves 2,3: same rows, ch [512,1024). f32 partials combined via LDS at end.
__global__ __launch_bounds__(256, 2) void proj_kernel(const float* __restrict__ x,
                                                      const f16* __restrict__ wf,
                                                      const float* __restrict__ bq,
                                                      const float* __restrict__ bk,
                                                      const float* __restrict__ bv,
                                                      f16* __restrict__ qs,
                                                      f16* __restrict__ ks,
                                                      f16* __restrict__ vT) {
  __shared__ __attribute__((aligned(16))) char smem[2 * 192 * SPW * 2];
  f16(*lw)[192][SPW] = (f16(*)[192][SPW])smem;         // [half][row(3*64)][32ch pad]
  f32x4(*comb)[64][12] = (f32x4(*)[64][12])smem;       // acc exchange (reuses smem)

  const int tid = threadIdx.x;
  const int lane = tid & 63, w = tid >> 6;
  const int n = lane & 15, quad = lane >> 4;
  const int h = w >> 1;                 // channel half
  const int rw = w & 1;                 // row half
  const int rowbase = blockIdx.x * 32;
  const int row0w = rowbase + rw * 16;  // this wave's 16 rows

  // staging map: 6 chunks/thread, id = tid + 256*i -> (half, row, col8)
  int sh[6], srow[6], sc8[6];
#pragma unroll
  for (int i = 0; i < 6; ++i) {
    const int id = tid + 256 * i;
    sh[i] = id / 768;
    const int rem = id - sh[i] * 768;
    srow[i] = rem >> 2;
    sc8[i] = (rem & 3) * 8;
  }

  f32x4 acc[3][4];
#pragma unroll
  for (int m_ = 0; m_ < 3; ++m_)
#pragma unroll
    for (int t_ = 0; t_ < 4; ++t_) acc[m_][t_] = (f32x4){0.f, 0.f, 0.f, 0.f};

  const float* xrow = x + (size_t)(row0w + n) * CDIM + h * 512 + quad * 8;

  f16x8 wreg[6];
  f32x4 xr0, xr1;
#define WLOADP(KC)                                                                     \
  {                                                                                    \
    _Pragma("unroll") for (int i = 0; i < 6; ++i)                                      \
        wreg[i] = *(const f16x8*)(wf + (size_t)srow[i] * CDIM + sh[i] * 512 + (KC) + sc8[i]); \
  }
#define XLOADP(KC)                          \
  {                                         \
    xr0 = *(const f32x4*)(xrow + (KC));     \
    xr1 = *(const f32x4*)(xrow + (KC) + 4); \
  }

  WLOADP(0);
  XLOADP(0);
  for (int kc = 0; kc < 512; kc += 32) {
#pragma unroll
    for (int i = 0; i < 6; ++i) *(f16x8*)&lw[sh[i]][srow[i]][sc8[i]] = wreg[i];
    __syncthreads();
    if (kc + 32 < 512) WLOADP(kc + 32);
    const f16x8 a = cvt8(xr0, xr1);
    if (kc + 32 < 512) XLOADP(kc + 32);
#pragma unroll
    for (int mat = 0; mat < 3; ++mat)
#pragma unroll
      for (int tile = 0; tile < 4; ++tile) {
        const f16x8 bf = *(const f16x8*)&lw[h][mat * 64 + tile * 16 + n][quad * 8];
        acc[mat][tile] = MFMA32(a, bf, acc[mat][tile]);
      }
    __syncthreads();
  }

  // combine channel halves: waves 2,3 -> LDS -> waves 0,1 add
  if (h == 1) {
#pragma unroll
    for (int m_ = 0; m_ < 3; ++m_)
#pragma unroll
      for (int t_ = 0; t_ < 4; ++t_) comb[rw][lane][m_ * 4 + t_] = acc[m_][t_];
  }
  __syncthreads();
  if (h == 1) return;
#pragma unroll
  for (int m_ = 0; m_ < 3; ++m_)
#pragma unroll
    for (int t_ = 0; t_ < 4; ++t_) {
      const f32x4 o = comb[rw][lane][m_ * 4 + t_];
#pragma unroll
      for (int r = 0; r < 4; ++r) acc[m_][t_][r] += o[r];
    }

  const float* bias_p[3] = {bq, bk, bv};
#pragma unroll
  for (int mat = 0; mat < 3; ++mat)
#pragma unroll
    for (int tile = 0; tile < 4; ++tile) {
      const int d = tile * 16 + n;
      const float bias = bias_p[mat][d];
      const int r0 = row0w + quad * 4;   // C-layout: row=quad*4+r, col=n
      f32x4 a = acc[mat][tile];
      if (mat == 0) {
#pragma unroll
        for (int r = 0; r < 4; ++r)
          qs[(size_t)(r0 + r) * DDIM + d] = (f16)((a[r] + bias) * QSCALE);
      } else if (mat == 1) {
#pragma unroll
        for (int r = 0; r < 4; ++r)
          ks[(size_t)(r0 + r) * DDIM + d] = (f16)(a[r] + bias);
      } else {
        const int bb = r0 >> 12;
        const int t = r0 & (SEQ - 1);
        *(f16x4*)(vT + (size_t)(bb * 64 + d) * SEQ + t) =
            cvt4(a[0] + bias, a[1] + bias, a[2] + bias, a[3] + bias);
      }
    }
}

// ---------------- flash attention: transposed softmax, P stays in registers ----
// S' = K·Q^T (C-layout row=key, col=q). PV uses mfma_16x16x16: its B-fragment
// layout [k=quad*4+j][n] IS the S' C-layout -> no LDS round-trip for P.
template <int NSPLIT>
__global__ __launch_bounds__(256, 4) void attn_kernel(const f16* __restrict__ qs,
                                                      const f16* __restrict__ ks,
                                                      const f16* __restrict__ vT,
                                                      float* __restrict__ outp,
                                                      f16* __restrict__ pacc,
                                                      float* __restrict__ pm,
                                                      float* __restrict__ pl) {
  __shared__ __attribute__((aligned(16))) f16 lk[64][SPA];  // [key][d]
  __shared__ __attribute__((aligned(16))) f16 lv[64][SPA];  // [d][key]
  const int tid = threadIdx.x, lane = tid & 63, w = tid >> 6;
  const int n = lane & 15, quad = lane >> 4;
  const int split = blockIdx.x % NSPLIT;
  const int rowblk = blockIdx.x / NSPLIT;
  const int row0 = rowblk * 128 + w * 32;
  const int bb = row0 >> 12;
  const int kbase = split * (SEQ / NSPLIT);
  const int NC = SEQ / NSPLIT / 64;

  const f16* kb = ks + (size_t)bb * SEQ * DDIM;
  const f16* vb = vT + (size_t)bb * DDIM * SEQ;

  const int srow = tid >> 2;          // 0..63
  const int scol = (tid & 3) * 16;    // 0,16,32,48
  const f16* kgp = kb + (size_t)(kbase + srow) * DDIM + scol;
  const f16* vgp = vb + (size_t)srow * SEQ + kbase + scol;

  // persistent Q B-fragments (16x16x32): B[k=d=quad*8+j][col=q=n]
  f16x8 qf[2][2];
#pragma unroll
  for (int g = 0; g < 2; ++g)
#pragma unroll
    for (int hh = 0; hh < 2; ++hh)
      qf[g][hh] = *(const f16x8*)(qs + (size_t)(row0 + g * 16 + n) * DDIM + hh * 32 + quad * 8);

  f32x4 acc[2][4];
  float m[2] = {-1e30f, -1e30f}, ll[2] = {0.f, 0.f};
#pragma unroll
  for (int g = 0; g < 2; ++g)
#pragma unroll
    for (int t = 0; t < 4; ++t) acc[g][t] = (f32x4){0.f, 0.f, 0.f, 0.f};

  f16x8 kr0, kr1, vr0, vr1;
  auto gload = [&](int c) {
    const f16* kp = kgp + (size_t)c * 64 * DDIM;
    kr0 = *(const f16x8*)kp;
    kr1 = *(const f16x8*)(kp + 8);
    const f16* vp = vgp + c * 64;
    vr0 = *(const f16x8*)vp;
    vr1 = *(const f16x8*)(vp + 8);
  };

  gload(0);
  for (int c = 0; c < NC; ++c) {
    *(f16x8*)&lk[srow][scol] = kr0;
    *(f16x8*)&lk[srow][scol + 8] = kr1;
    *(f16x8*)&lv[srow][scol] = vr0;
    *(f16x8*)&lv[srow][scol + 8] = vr1;
    __syncthreads();
    if (c + 1 < NC) gload(c + 1);  // prefetch; drained by end-of-chunk barrier

    // S' = K·Q^T
    f32x4 s[2][4];
#pragma unroll
    for (int st = 0; st < 4; ++st) {
      const f16x8 klo = *(const f16x8*)&lk[st * 16 + n][quad * 8];
      const f16x8 khi = *(const f16x8*)&lk[st * 16 + n][32 + quad * 8];
#pragma unroll
      for (int g = 0; g < 2; ++g) {
        f32x4 z = (f32x4){0.f, 0.f, 0.f, 0.f};
        z = MFMA32(klo, qf[g][0], z);
        s[g][st] = MFMA32(khi, qf[g][1], z);
      }
    }

    // per-lane online softmax; P packed directly as 16x16x16 B-fragments
    f16x4 pq[2][4];
#pragma unroll
    for (int g = 0; g < 2; ++g) {
      f32x4 mx;
#pragma unroll
      for (int r = 0; r < 4; ++r)
        mx[r] = fmaxf(fmaxf(s[g][0][r], s[g][1][r]), fmaxf(s[g][2][r], s[g][3][r]));
      float mloc = fmaxf(fmaxf(mx[0], mx[1]), fmaxf(mx[2], mx[3]));
      mloc = fmaxf(mloc, __shfl_xor(mloc, 16));
      mloc = fmaxf(mloc, __shfl_xor(mloc, 32));
      const float mnew = fmaxf(m[g], mloc);
      const float alpha = __builtin_amdgcn_exp2f(m[g] - mnew);
      m[g] = mnew;
      float psum = 0.f;
#pragma unroll
      for (int st = 0; st < 4; ++st) {
        f32x4 p;
#pragma unroll
        for (int r = 0; r < 4; ++r) p[r] = __builtin_amdgcn_exp2f(s[g][st][r] - mnew);
        psum += (p[0] + p[1]) + (p[2] + p[3]);
        pq[g][st] = cvt4(p[0], p[1], p[2], p[3]);
      }
      ll[g] = ll[g] * alpha + psum;
#pragma unroll
      for (int t = 0; t < 4; ++t) acc[g][t] *= alpha;
    }

    // O^T += V^T·P^T : A = V^T frag [m=d][k=key quad*4+j], B = pq (in-register)
#pragma unroll
    for (int t = 0; t < 4; ++t)
#pragma unroll
      for (int st = 0; st < 4; ++st) {
        const f16x4 va = *(const f16x4*)&lv[t * 16 + n][st * 16 + quad * 4];
        acc[0][t] = MFMA16(va, pq[0][st], acc[0][t]);
        acc[1][t] = MFMA16(va, pq[1][st], acc[1][t]);
      }
    __syncthreads();
  }

  float lred[2];
#pragma unroll
  for (int g = 0; g < 2; ++g) {
    float l = ll[g];
    l += __shfl_xor(l, 16);
    l += __shfl_xor(l, 32);
    lred[g] = l;
  }

  if (NSPLIT == 1) {
#pragma unroll
    for (int g = 0; g < 2; ++g) {
      const float inv = 1.0f / lred[g];
      const int q = row0 + g * 16 + n;
#pragma unroll
      for (int t = 0; t < 4; ++t) {
        f32x4 o = acc[g][t];
#pragma unroll
        for (int r = 0; r < 4; ++r) o[r] *= inv;
        *(f32x4*)(outp + (size_t)q * DDIM + t * 16 + quad * 4) = o;
      }
    }
  } else {
#pragma unroll
    for (int g = 0; g < 2; ++g) {
      const int q = row0 + g * 16 + n;
#pragma unroll
      for (int t = 0; t < 4; ++t)
        *(f16x4*)(pacc + ((size_t)split * NROW + q) * DDIM + t * 16 + quad * 4) =
            cvt4(acc[g][t][0], acc[g][t][1], acc[g][t][2], acc[g][t][3]);
      if (quad == 0) {
        pm[split * NROW + q] = m[g];
        pl[split * NROW + q] = lred[g];
      }
    }
  }
}

// ---------------- split-K combine (f16 partials) ----------------
template <int NSPLIT>
__global__ __launch_bounds__(256) void combine_kernel(const f16* __restrict__ pacc,
                                                      const float* __restrict__ pm,
                                                      const float* __restrict__ pl,
                                                      float* __restrict__ out) {
  const int idx = blockIdx.x * 256 + threadIdx.x;  // NROW*16 units
  const int row = idx >> 4;
  const int c = (idx & 15) * 4;
  float mm = pm[row];
#pragma unroll
  for (int s = 1; s < NSPLIT; ++s) mm = fmaxf(mm, pm[s * NROW + row]);
  float L = 0.f;
  f32x4 o = (f32x4){0.f, 0.f, 0.f, 0.f};
#pragma unroll
  for (int s = 0; s < NSPLIT; ++s) {
    const float e = __builtin_amdgcn_exp2f(pm[s * NROW + row] - mm);
    L += pl[s * NROW + row] * e;
    const f16x4 a = *(const f16x4*)(pacc + ((size_t)s * NROW + row) * DDIM + c);
#pragma unroll
    for (int j = 0; j < 4; ++j) o[j] += (float)a[j] * e;
  }
  const float inv = 1.0f / L;
#pragma unroll
  for (int j = 0; j < 4; ++j) o[j] *= inv;
  *(f32x4*)(out + (size_t)row * DDIM + c) = o;
}

extern "C" void kernel_launch(void* const* d_in, const int* in_sizes, int n_in,
                              void* d_out, int out_size, void* d_ws, size_t ws_size,
                              hipStream_t stream) {
  const float* x  = (const float*)d_in[0];
  const float* Wq = (const float*)d_in[1];
  const float* bq = (const float*)d_in[2];
  const float* Wk = (const float*)d_in[3];
  const float* bk = (const float*)d_in[4];
  const float* Wv = (const float*)d_in[5];
  const float* bv = (const float*)d_in[6];
  float* out = (float*)d_out;

  f16* wf = (f16*)d_ws;                       // 3*64*1024 f16
  f16* qs = wf + 3 * 65536;
  f16* ks = qs + (size_t)NROW * DDIM;
  f16* vT = ks + (size_t)NROW * DDIM;
  f16* pacc = vT + (size_t)NROW * DDIM;       // [NSPL][NROW][64] f16
  float* pm = (float*)(pacc + (size_t)NSPL * NROW * DDIM);
  float* pl = pm + (size_t)NSPL * NROW;
  const size_t need = (size_t)((char*)(pl + (size_t)NSPL * NROW) - (char*)d_ws);

  prep_w_kernel<<<dim3(64), dim3(256), 0, stream>>>(Wq, Wk, Wv, wf);
  proj_kernel<<<dim3(512), dim3(256), 0, stream>>>(x, wf, bq, bk, bv, qs, ks, vT);

  if (ws_size >= need) {
    attn_kernel<NSPL><<<dim3(128 * NSPL), dim3(256), 0, stream>>>(qs, ks, vT, nullptr, pacc, pm, pl);
    combine_kernel<NSPL><<<dim3(NROW * 16 / 256), dim3(256), 0, stream>>>(pacc, pm, pl, out);
  } else {
    attn_kernel<1><<<dim3(128), dim3(256), 0, stream>>>(qs, ks, vT, out, nullptr, nullptr, nullptr);
  }
}